// Round 1
// baseline (353.529 us; speedup 1.0000x reference)
//
#include <hip/hip_runtime.h>
#include <hip/hip_bf16.h>

typedef float  f32x4 __attribute__((ext_vector_type(4)));
typedef short  s16x8 __attribute__((ext_vector_type(8)));

#define NB   1024
#define SEQ  64
#define DIM  512
#define NH   8
#define SCALE 0.044194173824159216f

static __device__ __forceinline__ unsigned short f2bf(float f) {
    unsigned u = __builtin_bit_cast(unsigned, f);
    u += 0x7FFFu + ((u >> 16) & 1u);
    return (unsigned short)(u >> 16);
}

static __device__ __forceinline__ f32x4 mma(s16x8 a, s16x8 b, f32x4 c) {
    return __builtin_amdgcn_mfma_f32_16x16x32_bf16(a, b, c, 0, 0, 0);
}

// Pre-kernel: convert Wq, Wc (f32 [512][512] row-major, [k][n]) into bf16
// B-fragment order: for m in {0,1}, tile 0..31 (16 cols), ks 0..15 (k0=ks*32),
// lane 0..63: 8 bf16 = W[k0 + (lane>>4)*8 + j][tile*16 + (lane&15)], j=0..7.
__global__ __launch_bounds__(256) void prep_weights(
    const float* __restrict__ Wq, const float* __restrict__ Wc,
    unsigned short* __restrict__ wf)
{
    int gid  = blockIdx.x * 256 + threadIdx.x;   // 0..65535
    int m    = gid >> 15;
    int tile = (gid >> 10) & 31;
    int ks   = (gid >> 6) & 15;
    int lane = gid & 63;
    const float* W = m ? Wc : Wq;
    int col = tile * 16 + (lane & 15);
    int k0  = ks * 32 + (lane >> 4) * 8;
    unsigned short* dst = wf + (size_t)gid * 8;
#pragma unroll
    for (int j = 0; j < 8; ++j)
        dst[j] = f2bf(W[(size_t)(k0 + j) * DIM + col]);
}

__global__ __launch_bounds__(256) void coattn(
    const float* __restrict__ query,
    const float* __restrict__ context,
    const float* __restrict__ bq,
    const float* __restrict__ bc,
    const unsigned short* __restrict__ wf,
    float* __restrict__ out)
{
    // padded: row strides 80 B / 144 B -> only 2-way LDS bank aliasing on b128 reads
    __shared__ unsigned short sX[2][SEQ][40];
    __shared__ unsigned short sT[4][SEQ][72];

    const int tid  = threadIdx.x;
    const int lane = tid & 63;
    const int wv   = tid >> 6;          // wave id 0..3
    const int l15  = lane & 15;
    const int l4   = lane >> 4;
    const int b    = blockIdx.x >> 1;
    const int half = blockIdx.x & 1;
    const int h    = half * 4 + wv;     // head this wave owns

    const float* gq = query   + (size_t)b * SEQ * DIM;
    const float* gc = context + (size_t)b * SEQ * DIM;

    const f32x4 fz = {0.f, 0.f, 0.f, 0.f};
    f32x4 accQ[4][4], accC[4][4];
#pragma unroll
    for (int i = 0; i < 4; ++i)
#pragma unroll
        for (int j = 0; j < 4; ++j) { accQ[i][j] = fz; accC[i][j] = fz; }

    // ================= Phase 1: projections =================
    for (int kc = 0; kc < DIM; kc += 32) {
#pragma unroll
        for (int rep = 0; rep < 2; ++rep) {
            int idx = rep * 256 + tid;
            int row = idx >> 3;
            int c4  = (idx & 7) * 4;
            float4 vq = *(const float4*)(gq + (size_t)row * DIM + kc + c4);
            float4 vc = *(const float4*)(gc + (size_t)row * DIM + kc + c4);
            unsigned uq0 = f2bf(vq.x) | ((unsigned)f2bf(vq.y) << 16);
            unsigned uq1 = f2bf(vq.z) | ((unsigned)f2bf(vq.w) << 16);
            unsigned uc0 = f2bf(vc.x) | ((unsigned)f2bf(vc.y) << 16);
            unsigned uc1 = f2bf(vc.z) | ((unsigned)f2bf(vc.w) << 16);
            *(uint2*)&sX[0][row][c4] = make_uint2(uq0, uq1);
            *(uint2*)&sX[1][row][c4] = make_uint2(uc0, uc1);
        }
        __syncthreads();

        s16x8 aq[4], ac[4], bqf[4], bcf[4];
        const int ksg = kc >> 5;
#pragma unroll
        for (int mt = 0; mt < 4; ++mt) {
            aq[mt] = *(const s16x8*)&sX[0][mt * 16 + l15][l4 * 8];
            ac[mt] = *(const s16x8*)&sX[1][mt * 16 + l15][l4 * 8];
        }
#pragma unroll
        for (int nt = 0; nt < 4; ++nt) {
            int tile = h * 4 + nt;
            size_t off = ((size_t)(tile * 16 + ksg) * 64 + lane) * 8;
            bqf[nt] = *(const s16x8*)(wf + off);
            bcf[nt] = *(const s16x8*)(wf + 262144 + off);
        }
#pragma unroll
        for (int mt = 0; mt < 4; ++mt)
#pragma unroll
            for (int nt = 0; nt < 4; ++nt) {
                accQ[mt][nt] = mma(aq[mt], bqf[nt], accQ[mt][nt]);
                accC[mt][nt] = mma(ac[mt], bcf[nt], accC[mt][nt]);
            }
        __syncthreads();
    }

    // bias add (C/D layout: row = (l>>4)*4+reg, col = l&15)
#pragma unroll
    for (int nt = 0; nt < 4; ++nt) {
        float bqv = bq[h * 64 + nt * 16 + l15];
        float bcv = bc[h * 64 + nt * 16 + l15];
#pragma unroll
        for (int mt = 0; mt < 4; ++mt)
#pragma unroll
            for (int r = 0; r < 4; ++r) { accQ[mt][nt][r] += bqv; accC[mt][nt][r] += bcv; }
    }

    unsigned short (*T)[72] = sT[wv];

    // ===== Qp -> LDS; load Qp A-frags (contig) and Qp B-frags (strided) =====
#pragma unroll
    for (int mt = 0; mt < 4; ++mt)
#pragma unroll
        for (int nt = 0; nt < 4; ++nt)
#pragma unroll
            for (int r = 0; r < 4; ++r)
                T[mt * 16 + l4 * 4 + r][nt * 16 + l15] = f2bf(accQ[mt][nt][r]);
    __syncthreads();

    s16x8 qa[4][2], qb[4][2];
#pragma unroll
    for (int mt = 0; mt < 4; ++mt)
#pragma unroll
        for (int ks = 0; ks < 2; ++ks)
            qa[mt][ks] = *(const s16x8*)&T[mt * 16 + l15][ks * 32 + l4 * 8];
#pragma unroll
    for (int nt = 0; nt < 4; ++nt)
#pragma unroll
        for (int ks = 0; ks < 2; ++ks) {
            s16x8 v;
#pragma unroll
            for (int j = 0; j < 8; ++j)
                v[j] = (short)T[ks * 32 + l4 * 8 + j][nt * 16 + l15];
            qb[nt][ks] = v;
        }
    __syncthreads();

    // ===== Cp -> LDS; load Cp B-frags (contig; serves Cp^T as B operand) =====
#pragma unroll
    for (int mt = 0; mt < 4; ++mt)
#pragma unroll
        for (int nt = 0; nt < 4; ++nt)
#pragma unroll
            for (int r = 0; r < 4; ++r)
                T[mt * 16 + l4 * 4 + r][nt * 16 + l15] = f2bf(accC[mt][nt][r]);
    __syncthreads();

    s16x8 cb[4][2];
#pragma unroll
    for (int nt = 0; nt < 4; ++nt)
#pragma unroll
        for (int ks = 0; ks < 2; ++ks)
            cb[nt][ks] = *(const s16x8*)&T[nt * 16 + l15][ks * 32 + l4 * 8];
    __syncthreads();

    // ===== attn = Qp @ Cp^T (raw logits; SCALE folded into softmax) =====
    f32x4 Sc[4][4];
#pragma unroll
    for (int i = 0; i < 4; ++i)
#pragma unroll
        for (int j = 0; j < 4; ++j) Sc[i][j] = fz;
#pragma unroll
    for (int ks = 0; ks < 2; ++ks)
#pragma unroll
        for (int mt = 0; mt < 4; ++mt)
#pragma unroll
            for (int nt = 0; nt < 4; ++nt)
                Sc[mt][nt] = mma(qa[mt][ks], cb[nt][ks], Sc[mt][nt]);

    // ===== softmax over k (rows): P1 -> LDS =====
#pragma unroll
    for (int mt = 0; mt < 4; ++mt)
#pragma unroll
        for (int r = 0; r < 4; ++r) {
            float m = fmaxf(fmaxf(Sc[mt][0][r], Sc[mt][1][r]),
                            fmaxf(Sc[mt][2][r], Sc[mt][3][r]));
            m = fmaxf(m, __shfl_xor(m, 1));
            m = fmaxf(m, __shfl_xor(m, 2));
            m = fmaxf(m, __shfl_xor(m, 4));
            m = fmaxf(m, __shfl_xor(m, 8));
            float e[4], s = 0.f;
#pragma unroll
            for (int nt = 0; nt < 4; ++nt) { e[nt] = __expf(SCALE * (Sc[mt][nt][r] - m)); s += e[nt]; }
            s += __shfl_xor(s, 1);
            s += __shfl_xor(s, 2);
            s += __shfl_xor(s, 4);
            s += __shfl_xor(s, 8);
            float inv = 1.f / s;
            int row = mt * 16 + l4 * 4 + r;
#pragma unroll
            for (int nt = 0; nt < 4; ++nt)
                T[row][nt * 16 + l15] = f2bf(e[nt] * inv);
        }
    __syncthreads();

    s16x8 pa[4][2];
#pragma unroll
    for (int mt = 0; mt < 4; ++mt)
#pragma unroll
        for (int ks = 0; ks < 2; ++ks)
            pa[mt][ks] = *(const s16x8*)&T[mt * 16 + l15][ks * 32 + l4 * 8];
    __syncthreads();

    // ===== softmax over q (cols): P2^T -> LDS =====
#pragma unroll
    for (int nt = 0; nt < 4; ++nt) {
        float m = -1e30f;
#pragma unroll
        for (int mt = 0; mt < 4; ++mt)
#pragma unroll
            for (int r = 0; r < 4; ++r) m = fmaxf(m, Sc[mt][nt][r]);
        m = fmaxf(m, __shfl_xor(m, 16));
        m = fmaxf(m, __shfl_xor(m, 32));
        float ee[4][4], s = 0.f;
#pragma unroll
        for (int mt = 0; mt < 4; ++mt)
#pragma unroll
            for (int r = 0; r < 4; ++r) { ee[mt][r] = __expf(SCALE * (Sc[mt][nt][r] - m)); s += ee[mt][r]; }
        s += __shfl_xor(s, 16);
        s += __shfl_xor(s, 32);
        float inv = 1.f / s;
        int krow = nt * 16 + l15;
#pragma unroll
        for (int mt = 0; mt < 4; ++mt)
#pragma unroll
            for (int r = 0; r < 4; ++r)
                T[krow][mt * 16 + l4 * 4 + r] = f2bf(ee[mt][r] * inv);
    }
    __syncthreads();

    s16x8 p2a[4][2];
#pragma unroll
    for (int mt = 0; mt < 4; ++mt)
#pragma unroll
        for (int ks = 0; ks < 2; ++ks)
            p2a[mt][ks] = *(const s16x8*)&T[mt * 16 + l15][ks * 32 + l4 * 8];

    // ===== c_coattn = P1 @ Cp^T ; store =====
    f32x4 O[4][4];
#pragma unroll
    for (int i = 0; i < 4; ++i)
#pragma unroll
        for (int j = 0; j < 4; ++j) O[i][j] = fz;
#pragma unroll
    for (int ks = 0; ks < 2; ++ks)
#pragma unroll
        for (int mt = 0; mt < 4; ++mt)
#pragma unroll
            for (int nt = 0; nt < 4; ++nt)
                O[mt][nt] = mma(pa[mt][ks], cb[nt][ks], O[mt][nt]);

    float* cO = out;
#pragma unroll
    for (int mt = 0; mt < 4; ++mt)
#pragma unroll
        for (int nt = 0; nt < 4; ++nt)
#pragma unroll
            for (int r = 0; r < 4; ++r) {
                int qrow = mt * 16 + l4 * 4 + r;
                cO[((size_t)b * SEQ + qrow) * (NH * 64) + h * 64 + nt * 16 + l15] = O[mt][nt][r];
            }

    // ===== q_coattn = P2^T @ Qp ; store =====
#pragma unroll
    for (int i = 0; i < 4; ++i)
#pragma unroll
        for (int j = 0; j < 4; ++j) O[i][j] = fz;
#pragma unroll
    for (int ks = 0; ks < 2; ++ks)
#pragma unroll
        for (int mt = 0; mt < 4; ++mt)
#pragma unroll
            for (int nt = 0; nt < 4; ++nt)
                O[mt][nt] = mma(p2a[mt][ks], qb[nt][ks], O[mt][nt]);

    float* qO = out + (size_t)NB * SEQ * NH * 64;
#pragma unroll
    for (int mt = 0; mt < 4; ++mt)
#pragma unroll
        for (int nt = 0; nt < 4; ++nt)
#pragma unroll
            for (int r = 0; r < 4; ++r) {
                int krow = mt * 16 + l4 * 4 + r;
                qO[((size_t)b * SEQ + krow) * (NH * 64) + h * 64 + nt * 16 + l15] = O[mt][nt][r];
            }
}

extern "C" void kernel_launch(void* const* d_in, const int* in_sizes, int n_in,
                              void* d_out, int out_size, void* d_ws, size_t ws_size,
                              hipStream_t stream) {
    const float* query   = (const float*)d_in[0];
    const float* context = (const float*)d_in[1];
    const float* Wq      = (const float*)d_in[2];
    const float* bq      = (const float*)d_in[3];
    const float* Wc      = (const float*)d_in[4];
    const float* bc      = (const float*)d_in[5];
    unsigned short* wfrag = (unsigned short*)d_ws;   // 1 MB of frag-ordered bf16 weights
    float* out = (float*)d_out;

    prep_weights<<<256, 256, 0, stream>>>(Wq, Wc, wfrag);
    coattn<<<NB * 2, 256, 0, stream>>>(query, context, bq, bc, wfrag, out);
}